// Round 1
// baseline (92.386 us; speedup 1.0000x reference)
//
#include <hip/hip_runtime.h>
#include <math.h>

#define EPS_REG 1e-6f
#define MIN_EIG_F 1e-4f
#define NCH 64   // column-sum chunks

// ---------- 3x3 helpers ----------

__device__ __forceinline__ void sym_inv3(const float m[3][3], float o[3][3]) {
    float c00 = m[1][1]*m[2][2] - m[1][2]*m[2][1];
    float c01 = m[1][2]*m[2][0] - m[1][0]*m[2][2];
    float c02 = m[1][0]*m[2][1] - m[1][1]*m[2][0];
    float det = m[0][0]*c00 + m[0][1]*c01 + m[0][2]*c02;
    float inv = 1.0f / det;
    o[0][0] = c00*inv;
    o[1][0] = c01*inv;
    o[2][0] = c02*inv;
    o[0][1] = (m[0][2]*m[2][1]-m[0][1]*m[2][2])*inv;
    o[1][1] = (m[0][0]*m[2][2]-m[0][2]*m[2][0])*inv;
    o[2][1] = (m[0][1]*m[2][0]-m[0][0]*m[2][1])*inv;
    o[0][2] = (m[0][1]*m[1][2]-m[0][2]*m[1][1])*inv;
    o[1][2] = (m[0][2]*m[1][0]-m[0][0]*m[1][2])*inv;
    o[2][2] = (m[0][0]*m[1][1]-m[0][1]*m[1][0])*inv;
}

__device__ __forceinline__ void jrot(float A[3][3], float V[3][3], int p, int q) {
    float apq = A[p][q];
    if (fabsf(apq) < 1e-20f) return;
    float theta = (A[q][q] - A[p][p]) / (2.0f * apq);
    float t = 1.0f / (fabsf(theta) + sqrtf(1.0f + theta*theta));
    if (theta < 0.0f) t = -t;
    float c = 1.0f / sqrtf(1.0f + t*t);
    float s = t * c;
    int r = 3 - p - q;
    float app = A[p][p], aqq = A[q][q];
    A[p][p] = app - t*apq;
    A[q][q] = aqq + t*apq;
    A[p][q] = 0.0f; A[q][p] = 0.0f;
    float arp = A[r][p], arq = A[r][q];
    A[r][p] = c*arp - s*arq; A[p][r] = A[r][p];
    A[r][q] = s*arp + c*arq; A[q][r] = A[r][q];
    #pragma unroll
    for (int k = 0; k < 3; k++) {
        float vkp = V[k][p], vkq = V[k][q];
        V[k][p] = c*vkp - s*vkq;
        V[k][q] = s*vkp + c*vkq;
    }
}

// ---------- kernel A: per-point precompute ----------
// Lp, Lq, S: symmetric storage (00,01,02,11,12,22); Rm: full 9
__global__ void precompute_kernel(const float* __restrict__ Sp,
                                  const float* __restrict__ Sq,
                                  const float* __restrict__ phi,
                                  float* __restrict__ Lp,
                                  float* __restrict__ Lq,
                                  float* __restrict__ Rm,
                                  float* __restrict__ S,
                                  int BN) {
    int t = blockIdx.x * blockDim.x + threadIdx.x;
    if (t >= BN) return;

    float m[3][3], lq[3][3], lp[3][3];
    const float* p = Sq + (size_t)t * 9;
    #pragma unroll
    for (int i = 0; i < 3; i++)
        #pragma unroll
        for (int j = 0; j < 3; j++) m[i][j] = p[i*3 + j];
    m[0][0] += EPS_REG; m[1][1] += EPS_REG; m[2][2] += EPS_REG;
    sym_inv3(m, lq);

    p = Sp + (size_t)t * 9;
    #pragma unroll
    for (int i = 0; i < 3; i++)
        #pragma unroll
        for (int j = 0; j < 3; j++) m[i][j] = p[i*3 + j];
    m[0][0] += EPS_REG; m[1][1] += EPS_REG; m[2][2] += EPS_REG;
    sym_inv3(m, lp);

    float* o = Lq + (size_t)t * 6;
    o[0]=lq[0][0]; o[1]=lq[0][1]; o[2]=lq[0][2]; o[3]=lq[1][1]; o[4]=lq[1][2]; o[5]=lq[2][2];
    o = Lp + (size_t)t * 6;
    o[0]=lp[0][0]; o[1]=lp[0][1]; o[2]=lp[0][2]; o[3]=lp[1][1]; o[4]=lp[1][2]; o[5]=lp[2][2];

    // Rodrigues: R = I + a*K + b*K^2, K = hat(phi), exact expm for skew input
    float w0 = phi[(size_t)t*3], w1 = phi[(size_t)t*3+1], w2 = phi[(size_t)t*3+2];
    float th2 = w0*w0 + w1*w1 + w2*w2;
    float th = sqrtf(th2);
    float a, b;
    if (th < 1e-4f) { a = 1.0f - th2*(1.0f/6.0f); b = 0.5f - th2*(1.0f/24.0f); }
    else            { a = sinf(th)/th;            b = (1.0f - cosf(th))/th2; }
    float R[3][3];
    R[0][0] = 1.0f + b*(w0*w0 - th2); R[0][1] = -a*w2 + b*w0*w1;        R[0][2] =  a*w1 + b*w0*w2;
    R[1][0] =  a*w2 + b*w0*w1;        R[1][1] = 1.0f + b*(w1*w1 - th2); R[1][2] = -a*w0 + b*w1*w2;
    R[2][0] = -a*w1 + b*w0*w2;        R[2][1] =  a*w0 + b*w1*w2;        R[2][2] = 1.0f + b*(w2*w2 - th2);
    o = Rm + (size_t)t * 9;
    #pragma unroll
    for (int i = 0; i < 3; i++)
        #pragma unroll
        for (int j = 0; j < 3; j++) o[i*3 + j] = R[i][j];

    // S = R^T * Lq * R
    float U[3][3], Sv[3][3];
    #pragma unroll
    for (int i = 0; i < 3; i++)
        #pragma unroll
        for (int j = 0; j < 3; j++)
            U[i][j] = lq[i][0]*R[0][j] + lq[i][1]*R[1][j] + lq[i][2]*R[2][j];
    #pragma unroll
    for (int i = 0; i < 3; i++)
        #pragma unroll
        for (int j = 0; j < 3; j++)
            Sv[i][j] = R[0][i]*U[0][j] + R[1][i]*U[1][j] + R[2][i]*U[2][j];
    o = S + (size_t)t * 6;
    o[0]=Sv[0][0]; o[1]=Sv[0][1]; o[2]=Sv[0][2]; o[3]=Sv[1][1]; o[4]=Sv[1][2]; o[5]=Sv[2][2];
}

// ---------- kernel B: T[b,i,:] = sum_j beta[b,i,j] * S[b,j,:]  (one wave per row) ----------
__global__ void rowsum_kernel(const float* __restrict__ beta,
                              const float* __restrict__ S,
                              float* __restrict__ T,
                              int B, int N) {
    int wid  = threadIdx.x >> 6;
    int lane = threadIdx.x & 63;
    int wpb  = blockDim.x >> 6;
    int row  = blockIdx.x * wpb + wid;       // global row over B*N
    int BN = B * N;
    if (row >= BN) return;
    int b = row / N;
    const float* brow = beta + (size_t)row * N;
    const float* sb = S + (size_t)b * N * 6;

    float a0=0.f,a1=0.f,a2=0.f,a3=0.f,a4=0.f,a5=0.f;
    for (int j = lane; j < N; j += 64) {
        float w = brow[j];
        const float2* sp = (const float2*)(sb + (size_t)j * 6);
        float2 s01 = sp[0], s23 = sp[1], s45 = sp[2];
        a0 += w*s01.x; a1 += w*s01.y; a2 += w*s23.x;
        a3 += w*s23.y; a4 += w*s45.x; a5 += w*s45.y;
    }
    #pragma unroll
    for (int off = 32; off > 0; off >>= 1) {
        a0 += __shfl_xor(a0, off);
        a1 += __shfl_xor(a1, off);
        a2 += __shfl_xor(a2, off);
        a3 += __shfl_xor(a3, off);
        a4 += __shfl_xor(a4, off);
        a5 += __shfl_xor(a5, off);
    }
    if (lane == 0) {
        float* o = T + (size_t)row * 6;
        o[0]=a0; o[1]=a1; o[2]=a2; o[3]=a3; o[4]=a4; o[5]=a5;
    }
}

// ---------- kernel C: chunked column sums (deterministic, no atomics) ----------
__global__ void colsum_partial_kernel(const float* __restrict__ beta,
                                      float* __restrict__ partial, // B*NCH*N
                                      int B, int N) {
    int b  = blockIdx.x / NCH;
    int ch = blockIdx.x % NCH;
    int rows = (N + NCH - 1) / NCH;
    int r0 = ch * rows;
    int r1 = r0 + rows; if (r1 > N) r1 = N;
    for (int col = threadIdx.x; col < N; col += blockDim.x) {
        float acc = 0.0f;
        const float* p = beta + ((size_t)b * N + r0) * N + col;
        for (int r = r0; r < r1; r++) { acc += *p; p += N; }
        partial[((size_t)b * NCH + ch) * N + col] = acc;
    }
}

// ---------- kernel D: finalize ----------
__global__ void finalize_kernel(const float* __restrict__ Lp,
                                const float* __restrict__ Lq,
                                const float* __restrict__ Rm,
                                const float* __restrict__ T,
                                const float* __restrict__ partial,
                                float* __restrict__ out,
                                int B, int N) {
    int t = blockIdx.x * blockDim.x + threadIdx.x;
    int BN = B * N;
    if (t >= BN) return;
    int b = t / N;
    int i = t - b * N;

    float cs = 0.0f;
    #pragma unroll 8
    for (int c = 0; c < NCH; c++)
        cs += partial[((size_t)b * NCH + c) * N + i];

    const float* p = Rm + (size_t)t * 9;
    float R[3][3];
    #pragma unroll
    for (int ii = 0; ii < 3; ii++)
        #pragma unroll
        for (int jj = 0; jj < 3; jj++) R[ii][jj] = p[ii*3 + jj];

    const float* tp = T + (size_t)t * 6;
    float Tm[3][3] = {{tp[0],tp[1],tp[2]},{tp[1],tp[3],tp[4]},{tp[2],tp[4],tp[5]}};
    const float* lpp = Lp + (size_t)t * 6;
    const float* lqp = Lq + (size_t)t * 6;
    float Lpf[3][3] = {{lpp[0],lpp[1],lpp[2]},{lpp[1],lpp[3],lpp[4]},{lpp[2],lpp[4],lpp[5]}};
    float Lqf[3][3] = {{lqp[0],lqp[1],lqp[2]},{lqp[1],lqp[3],lqp[4]},{lqp[2],lqp[4],lqp[5]}};

    // M_in = R * Tm * R^T
    float U[3][3], M[3][3];
    #pragma unroll
    for (int ii = 0; ii < 3; ii++)
        #pragma unroll
        for (int jj = 0; jj < 3; jj++)
            U[ii][jj] = R[ii][0]*Tm[0][jj] + R[ii][1]*Tm[1][jj] + R[ii][2]*Tm[2][jj];
    #pragma unroll
    for (int ii = 0; ii < 3; ii++)
        #pragma unroll
        for (int jj = 0; jj < 3; jj++) {
            float min_ij = U[ii][0]*R[jj][0] + U[ii][1]*R[jj][1] + U[ii][2]*R[jj][2];
            M[ii][jj] = Lpf[ii][jj] + min_ij + cs * Lqf[ii][jj];
        }
    // symmetrize (matches reference)
    float A[3][3];
    #pragma unroll
    for (int ii = 0; ii < 3; ii++)
        #pragma unroll
        for (int jj = 0; jj < 3; jj++) A[ii][jj] = 0.5f * (M[ii][jj] + M[jj][ii]);

    // Jacobi eigensolve, 6 sweeps
    float V[3][3] = {{1,0,0},{0,1,0},{0,0,1}};
    #pragma unroll
    for (int sweep = 0; sweep < 6; sweep++) {
        jrot(A, V, 0, 1);
        jrot(A, V, 0, 2);
        jrot(A, V, 1, 2);
    }
    float w0 = fmaxf(A[0][0], MIN_EIG_F);
    float w1 = fmaxf(A[1][1], MIN_EIG_F);
    float w2 = fmaxf(A[2][2], MIN_EIG_F);
    float iw0 = 1.0f/w0, iw1 = 1.0f/w1, iw2 = 1.0f/w2;

    float* opd = out + (size_t)t * 9;
    float* oin = out + (size_t)BN * 9 + (size_t)t * 9;
    #pragma unroll
    for (int ii = 0; ii < 3; ii++)
        #pragma unroll
        for (int jj = 0; jj < 3; jj++) {
            float pd = V[ii][0]*w0*V[jj][0] + V[ii][1]*w1*V[jj][1] + V[ii][2]*w2*V[jj][2];
            float iv = V[ii][0]*iw0*V[jj][0] + V[ii][1]*iw1*V[jj][1] + V[ii][2]*iw2*V[jj][2];
            opd[ii*3 + jj] = pd;
            oin[ii*3 + jj] = iv;
        }
}

extern "C" void kernel_launch(void* const* d_in, const int* in_sizes, int n_in,
                              void* d_out, int out_size, void* d_ws, size_t ws_size,
                              hipStream_t stream) {
    const float* Sp   = (const float*)d_in[0];
    const float* Sq   = (const float*)d_in[1];
    const float* phi  = (const float*)d_in[2];
    const float* beta = (const float*)d_in[3];
    // d_in[4] = generators (fixed so(3) basis; Rodrigues is the closed form)

    int BN = in_sizes[2] / 3;                 // B*N
    int N  = (int)((long long)in_sizes[3] / BN);
    int B  = BN / N;

    float* ws = (float*)d_ws;
    float* Lp = ws;                   // BN*6
    float* Lq = Lp + (size_t)BN * 6;  // BN*6
    float* Rm = Lq + (size_t)BN * 6;  // BN*9
    float* S  = Rm + (size_t)BN * 9;  // BN*6
    float* T  = S  + (size_t)BN * 6;  // BN*6
    float* partial = T + (size_t)BN * 6; // B*NCH*N

    float* outf = (float*)d_out;

    precompute_kernel<<<(BN + 255)/256, 256, 0, stream>>>(Sp, Sq, phi, Lp, Lq, Rm, S, BN);

    int wpb = 4;                               // 4 waves (rows) per 256-thread block
    int blocksB = (BN + wpb - 1) / wpb;
    rowsum_kernel<<<blocksB, 256, 0, stream>>>(beta, S, T, B, N);

    colsum_partial_kernel<<<B * NCH, 256, 0, stream>>>(beta, partial, B, N);

    finalize_kernel<<<(BN + 255)/256, 256, 0, stream>>>(Lp, Lq, Rm, T, partial, outf, B, N);
}

// Round 2
// 35.392 us; speedup vs baseline: 2.6104x; 2.6104x over previous
//
#include <hip/hip_runtime.h>
#include <math.h>

#define EPS_REG 1e-6f
#define MIN_EIG_F 1e-4f
#define NCH 32      // column-sum row chunks
#define CTILE 256   // column-sum columns per block

// ---------- 3x3 helpers ----------

__device__ __forceinline__ void sym_inv3(const float m[3][3], float o[3][3]) {
    float c00 = m[1][1]*m[2][2] - m[1][2]*m[2][1];
    float c01 = m[1][2]*m[2][0] - m[1][0]*m[2][2];
    float c02 = m[1][0]*m[2][1] - m[1][1]*m[2][0];
    float det = m[0][0]*c00 + m[0][1]*c01 + m[0][2]*c02;
    float inv = 1.0f / det;
    o[0][0] = c00*inv;
    o[1][0] = c01*inv;
    o[2][0] = c02*inv;
    o[0][1] = (m[0][2]*m[2][1]-m[0][1]*m[2][2])*inv;
    o[1][1] = (m[0][0]*m[2][2]-m[0][2]*m[2][0])*inv;
    o[2][1] = (m[0][1]*m[2][0]-m[0][0]*m[2][1])*inv;
    o[0][2] = (m[0][1]*m[1][2]-m[0][2]*m[1][1])*inv;
    o[1][2] = (m[0][2]*m[1][0]-m[0][0]*m[1][2])*inv;
    o[2][2] = (m[0][0]*m[1][1]-m[0][1]*m[1][0])*inv;
}

__device__ __forceinline__ void jrot(float A[3][3], float V[3][3], int p, int q) {
    float apq = A[p][q];
    if (fabsf(apq) < 1e-20f) return;
    float theta = (A[q][q] - A[p][p]) / (2.0f * apq);
    float t = 1.0f / (fabsf(theta) + sqrtf(1.0f + theta*theta));
    if (theta < 0.0f) t = -t;
    float c = 1.0f / sqrtf(1.0f + t*t);
    float s = t * c;
    int r = 3 - p - q;
    float apq_t = t*apq;
    A[p][p] -= apq_t;
    A[q][q] += apq_t;
    A[p][q] = 0.0f; A[q][p] = 0.0f;
    float arp = A[r][p], arq = A[r][q];
    A[r][p] = c*arp - s*arq; A[p][r] = A[r][p];
    A[r][q] = s*arp + c*arq; A[q][r] = A[r][q];
    #pragma unroll
    for (int k = 0; k < 3; k++) {
        float vkp = V[k][p], vkq = V[k][q];
        V[k][p] = c*vkp - s*vkq;
        V[k][q] = s*vkp + c*vkq;
    }
}

// ---------- kernel A: per-point precompute ----------
__global__ void precompute_kernel(const float* __restrict__ Sp,
                                  const float* __restrict__ Sq,
                                  const float* __restrict__ phi,
                                  float* __restrict__ Lp,
                                  float* __restrict__ Lq,
                                  float* __restrict__ Rm,
                                  float* __restrict__ S,
                                  int BN) {
    int t = blockIdx.x * blockDim.x + threadIdx.x;
    if (t >= BN) return;

    float m[3][3], lq[3][3], lp[3][3];
    const float* p = Sq + (size_t)t * 9;
    #pragma unroll
    for (int i = 0; i < 3; i++)
        #pragma unroll
        for (int j = 0; j < 3; j++) m[i][j] = p[i*3 + j];
    m[0][0] += EPS_REG; m[1][1] += EPS_REG; m[2][2] += EPS_REG;
    sym_inv3(m, lq);

    p = Sp + (size_t)t * 9;
    #pragma unroll
    for (int i = 0; i < 3; i++)
        #pragma unroll
        for (int j = 0; j < 3; j++) m[i][j] = p[i*3 + j];
    m[0][0] += EPS_REG; m[1][1] += EPS_REG; m[2][2] += EPS_REG;
    sym_inv3(m, lp);

    float* o = Lq + (size_t)t * 6;
    o[0]=lq[0][0]; o[1]=lq[0][1]; o[2]=lq[0][2]; o[3]=lq[1][1]; o[4]=lq[1][2]; o[5]=lq[2][2];
    o = Lp + (size_t)t * 6;
    o[0]=lp[0][0]; o[1]=lp[0][1]; o[2]=lp[0][2]; o[3]=lp[1][1]; o[4]=lp[1][2]; o[5]=lp[2][2];

    // Rodrigues: R = I + a*K + b*K^2, exact expm for skew input
    float w0 = phi[(size_t)t*3], w1 = phi[(size_t)t*3+1], w2 = phi[(size_t)t*3+2];
    float th2 = w0*w0 + w1*w1 + w2*w2;
    float th = sqrtf(th2);
    float a, b;
    if (th < 1e-4f) { a = 1.0f - th2*(1.0f/6.0f); b = 0.5f - th2*(1.0f/24.0f); }
    else            { a = sinf(th)/th;            b = (1.0f - cosf(th))/th2; }
    float R[3][3];
    R[0][0] = 1.0f + b*(w0*w0 - th2); R[0][1] = -a*w2 + b*w0*w1;        R[0][2] =  a*w1 + b*w0*w2;
    R[1][0] =  a*w2 + b*w0*w1;        R[1][1] = 1.0f + b*(w1*w1 - th2); R[1][2] = -a*w0 + b*w1*w2;
    R[2][0] = -a*w1 + b*w0*w2;        R[2][1] =  a*w0 + b*w1*w2;        R[2][2] = 1.0f + b*(w2*w2 - th2);
    o = Rm + (size_t)t * 9;
    #pragma unroll
    for (int i = 0; i < 3; i++)
        #pragma unroll
        for (int j = 0; j < 3; j++) o[i*3 + j] = R[i][j];

    // S = R^T * Lq * R
    float U[3][3], Sv[3][3];
    #pragma unroll
    for (int i = 0; i < 3; i++)
        #pragma unroll
        for (int j = 0; j < 3; j++)
            U[i][j] = lq[i][0]*R[0][j] + lq[i][1]*R[1][j] + lq[i][2]*R[2][j];
    #pragma unroll
    for (int i = 0; i < 3; i++)
        #pragma unroll
        for (int j = 0; j < 3; j++)
            Sv[i][j] = R[0][i]*U[0][j] + R[1][i]*U[1][j] + R[2][i]*U[2][j];
    o = S + (size_t)t * 6;
    o[0]=Sv[0][0]; o[1]=Sv[0][1]; o[2]=Sv[0][2]; o[3]=Sv[1][1]; o[4]=Sv[1][2]; o[5]=Sv[2][2];
}

// ---------- kernel B: T[b,i,:] = sum_j beta[b,i,j] * S[b,j,:]  (one wave per row) ----------
__global__ void rowsum_kernel(const float* __restrict__ beta,
                              const float* __restrict__ S,
                              float* __restrict__ T,
                              int B, int N) {
    int wid  = threadIdx.x >> 6;
    int lane = threadIdx.x & 63;
    int wpb  = blockDim.x >> 6;
    int row  = blockIdx.x * wpb + wid;       // global row over B*N
    int BN = B * N;
    if (row >= BN) return;
    int b = row / N;
    const float* brow = beta + (size_t)row * N;
    const float* sb = S + (size_t)b * N * 6;

    float a0=0.f,a1=0.f,a2=0.f,a3=0.f,a4=0.f,a5=0.f;
    int n4 = N >> 2;
    const float4* brow4 = (const float4*)brow;
    for (int j4 = lane; j4 < n4; j4 += 64) {
        float4 w4 = brow4[j4];
        int j = j4 << 2;
        #pragma unroll
        for (int u = 0; u < 4; u++) {
            float w = (u == 0) ? w4.x : (u == 1) ? w4.y : (u == 2) ? w4.z : w4.w;
            const float2* sp = (const float2*)(sb + (size_t)(j + u) * 6);
            float2 s01 = sp[0], s23 = sp[1], s45 = sp[2];
            a0 += w*s01.x; a1 += w*s01.y; a2 += w*s23.x;
            a3 += w*s23.y; a4 += w*s45.x; a5 += w*s45.y;
        }
    }
    #pragma unroll
    for (int off = 32; off > 0; off >>= 1) {
        a0 += __shfl_xor(a0, off);
        a1 += __shfl_xor(a1, off);
        a2 += __shfl_xor(a2, off);
        a3 += __shfl_xor(a3, off);
        a4 += __shfl_xor(a4, off);
        a5 += __shfl_xor(a5, off);
    }
    if (lane == 0) {
        float* o = T + (size_t)row * 6;
        o[0]=a0; o[1]=a1; o[2]=a2; o[3]=a3; o[4]=a4; o[5]=a5;
    }
}

// ---------- kernel C: chunked column sums (deterministic, occupancy-fixed) ----------
// grid: B * NCH * (N/CTILE) blocks, CTILE threads; each thread sums N/NCH rows
// of ONE column (coalesced across threads), writes one partial element.
__global__ void colsum_partial_kernel(const float* __restrict__ beta,
                                      float* __restrict__ partial, // B*NCH*N
                                      int B, int N) {
    int ctiles = N / CTILE;
    int idx = blockIdx.x;
    int ct = idx % ctiles;
    int ch = (idx / ctiles) % NCH;
    int b  = idx / (ctiles * NCH);
    int col = ct * CTILE + threadIdx.x;
    if (col >= N) return;
    int rows = N / NCH;
    int r0 = ch * rows;
    const float* p = beta + ((size_t)b * N + r0) * N + col;
    float acc = 0.0f;
    #pragma unroll 8
    for (int r = 0; r < rows; r++) { acc += *p; p += N; }
    partial[((size_t)b * NCH + ch) * N + col] = acc;
}

// ---------- kernel D: finalize ----------
__global__ void finalize_kernel(const float* __restrict__ Lp,
                                const float* __restrict__ Lq,
                                const float* __restrict__ Rm,
                                const float* __restrict__ T,
                                const float* __restrict__ partial,
                                float* __restrict__ out,
                                int B, int N) {
    int t = blockIdx.x * blockDim.x + threadIdx.x;
    int BN = B * N;
    if (t >= BN) return;
    int b = t / N;
    int i = t - b * N;

    float cs = 0.0f;
    #pragma unroll 8
    for (int c = 0; c < NCH; c++)
        cs += partial[((size_t)b * NCH + c) * N + i];

    const float* p = Rm + (size_t)t * 9;
    float R[3][3];
    #pragma unroll
    for (int ii = 0; ii < 3; ii++)
        #pragma unroll
        for (int jj = 0; jj < 3; jj++) R[ii][jj] = p[ii*3 + jj];

    const float* tp = T + (size_t)t * 6;
    float Tm[3][3] = {{tp[0],tp[1],tp[2]},{tp[1],tp[3],tp[4]},{tp[2],tp[4],tp[5]}};
    const float* lpp = Lp + (size_t)t * 6;
    const float* lqp = Lq + (size_t)t * 6;
    float Lpf[3][3] = {{lpp[0],lpp[1],lpp[2]},{lpp[1],lpp[3],lpp[4]},{lpp[2],lpp[4],lpp[5]}};
    float Lqf[3][3] = {{lqp[0],lqp[1],lqp[2]},{lqp[1],lqp[3],lqp[4]},{lqp[2],lqp[4],lqp[5]}};

    // M_in = R * Tm * R^T
    float U[3][3], M[3][3];
    #pragma unroll
    for (int ii = 0; ii < 3; ii++)
        #pragma unroll
        for (int jj = 0; jj < 3; jj++)
            U[ii][jj] = R[ii][0]*Tm[0][jj] + R[ii][1]*Tm[1][jj] + R[ii][2]*Tm[2][jj];
    #pragma unroll
    for (int ii = 0; ii < 3; ii++)
        #pragma unroll
        for (int jj = 0; jj < 3; jj++) {
            float min_ij = U[ii][0]*R[jj][0] + U[ii][1]*R[jj][1] + U[ii][2]*R[jj][2];
            M[ii][jj] = Lpf[ii][jj] + min_ij + cs * Lqf[ii][jj];
        }
    // symmetrize (matches reference)
    float A[3][3];
    #pragma unroll
    for (int ii = 0; ii < 3; ii++)
        #pragma unroll
        for (int jj = 0; jj < 3; jj++) A[ii][jj] = 0.5f * (M[ii][jj] + M[jj][ii]);

    // Jacobi eigensolve, 6 sweeps
    float V[3][3] = {{1,0,0},{0,1,0},{0,0,1}};
    #pragma unroll
    for (int sweep = 0; sweep < 6; sweep++) {
        jrot(A, V, 0, 1);
        jrot(A, V, 0, 2);
        jrot(A, V, 1, 2);
    }
    float w0 = fmaxf(A[0][0], MIN_EIG_F);
    float w1 = fmaxf(A[1][1], MIN_EIG_F);
    float w2 = fmaxf(A[2][2], MIN_EIG_F);
    float iw0 = 1.0f/w0, iw1 = 1.0f/w1, iw2 = 1.0f/w2;

    float* opd = out + (size_t)t * 9;
    float* oin = out + (size_t)BN * 9 + (size_t)t * 9;
    #pragma unroll
    for (int ii = 0; ii < 3; ii++)
        #pragma unroll
        for (int jj = 0; jj < 3; jj++) {
            float pd = V[ii][0]*w0*V[jj][0] + V[ii][1]*w1*V[jj][1] + V[ii][2]*w2*V[jj][2];
            float iv = V[ii][0]*iw0*V[jj][0] + V[ii][1]*iw1*V[jj][1] + V[ii][2]*iw2*V[jj][2];
            opd[ii*3 + jj] = pd;
            oin[ii*3 + jj] = iv;
        }
}

extern "C" void kernel_launch(void* const* d_in, const int* in_sizes, int n_in,
                              void* d_out, int out_size, void* d_ws, size_t ws_size,
                              hipStream_t stream) {
    const float* Sp   = (const float*)d_in[0];
    const float* Sq   = (const float*)d_in[1];
    const float* phi  = (const float*)d_in[2];
    const float* beta = (const float*)d_in[3];

    int BN = in_sizes[2] / 3;                 // B*N
    int N  = (int)((long long)in_sizes[3] / BN);
    int B  = BN / N;

    float* ws = (float*)d_ws;
    float* Lp = ws;                   // BN*6
    float* Lq = Lp + (size_t)BN * 6;  // BN*6
    float* Rm = Lq + (size_t)BN * 6;  // BN*9
    float* S  = Rm + (size_t)BN * 9;  // BN*6
    float* T  = S  + (size_t)BN * 6;  // BN*6
    float* partial = T + (size_t)BN * 6; // B*NCH*N

    float* outf = (float*)d_out;

    // 64-thread blocks -> 64 blocks: spread tiny per-point work across CUs
    precompute_kernel<<<(BN + 63)/64, 64, 0, stream>>>(Sp, Sq, phi, Lp, Lq, Rm, S, BN);

    int wpb = 4;                               // 4 waves (rows) per 256-thread block
    int blocksB = (BN + wpb - 1) / wpb;
    rowsum_kernel<<<blocksB, 256, 0, stream>>>(beta, S, T, B, N);

    int ctiles = N / CTILE;
    colsum_partial_kernel<<<B * NCH * ctiles, CTILE, 0, stream>>>(beta, partial, B, N);

    finalize_kernel<<<(BN + 63)/64, 64, 0, stream>>>(Lp, Lq, Rm, T, partial, outf, B, N);
}